// Round 11
// baseline (47.780 us; speedup 1.0000x reference)
//
#include <hip/hip_runtime.h>

#define NN 512
#define NWD 128
#define NSLICES 96                      // B*P*Q
#define NROWS (NSLICES * NN)            // 49152
#define ALPHA 0.2f

typedef float vf4 __attribute__((ext_vector_type(4)));   // native vector: ok for nontemporal builtins

__device__ __forceinline__ float lrelu(float x) {
    return x > 0.f ? x : ALPHA * x;
}

__device__ __forceinline__ vf4 nt_load4(const float* p) {
    return __builtin_nontemporal_load(reinterpret_cast<const vf4*>(p));
}
__device__ __forceinline__ void nt_store4(float* p, vf4 v) {
    __builtin_nontemporal_store(v, reinterpret_cast<vf4*>(p));
}

// k0: wa1 = W@a1, wa2 = W@a2 -> global ws (256 floats).
// 16 blocks x 256 threads; each wave does ONE coalesced row-pair butterfly.
__global__ __launch_bounds__(256) void wa_kernel(const float* __restrict__ W,
                                                 const float* __restrict__ a,
                                                 float* __restrict__ wa) {
    const int t = threadIdx.x;
    const int wid = t >> 6;
    const int lane = t & 63;
    const int l5 = lane & 31;
    const int half = lane >> 5;

    const int k = (blockIdx.x * 4 + wid) * 2;      // W row pair (k, k+1)
    const float4 a1v = *reinterpret_cast<const float4*>(a + l5 * 4);
    const float4 a2v = *reinterpret_cast<const float4*>(a + NWD + l5 * 4);
    const float4 wv  = *reinterpret_cast<const float4*>(W + (long)k * NWD + lane * 4);

    float p1 = wv.x * a1v.x + wv.y * a1v.y + wv.z * a1v.z + wv.w * a1v.w;
    float p2 = wv.x * a2v.x + wv.y * a2v.y + wv.z * a2v.z + wv.w * a2v.w;
    #pragma unroll
    for (int off = 16; off > 0; off >>= 1) {
        p1 += __shfl_xor(p1, off);
        p2 += __shfl_xor(p2, off);
    }
    if (l5 == 0) {
        wa[k + half] = p1;              // wa1
        wa[NWD + k + half] = p2;        // wa2
    }
}

// k1: s1[g], s2[g] for all rows. 1536 blocks x 32 rows; 4 prefetched
// nt float4 loads per wave (st_feat is read-once -> don't cache it).
__global__ __launch_bounds__(256) void s_kernel(const float* __restrict__ st,
                                                const float* __restrict__ wa,
                                                float* __restrict__ s1,
                                                float* __restrict__ s2) {
    const int t = threadIdx.x;
    const int wid = t >> 6;
    const int lane = t & 63;
    const int l5 = lane & 31;
    const int half = lane >> 5;

    const float4 w1v = *reinterpret_cast<const float4*>(wa + l5 * 4);
    const float4 w2v = *reinterpret_cast<const float4*>(wa + NWD + l5 * 4);
    const long blockbase = (long)blockIdx.x * 32;    // 32 rows per block
    const long wavebase = blockbase + (long)wid * 8; // 8 rows = 4 rowpairs

    vf4 f[4];
    #pragma unroll
    for (int i = 0; i < 4; ++i)
        f[i] = nt_load4(st + (wavebase + i * 2) * NWD + lane * 4);

    #pragma unroll
    for (int i = 0; i < 4; ++i) {
        float p1 = f[i].x * w1v.x + f[i].y * w1v.y + f[i].z * w1v.z + f[i].w * w1v.w;
        float p2 = f[i].x * w2v.x + f[i].y * w2v.y + f[i].z * w2v.z + f[i].w * w2v.w;
        #pragma unroll
        for (int off = 16; off > 0; off >>= 1) {
            p1 += __shfl_xor(p1, off);
            p2 += __shfl_xor(p2, off);
        }
        if (l5 == 0) {
            const long g = wavebase + i * 2 + half;
            s1[g] = p1;
            s2[g] = p2;
        }
    }
}

// k2: streaming kernel. One wave per row; 8 cols/lane (2x float4).
// demand nt-loaded (read-once), out nt-stored (write-once) -> keep L2 for s2.
// No row-max: |e| <= ~15, exp <= 1.2e6 -- f32-safe (validated R6/R7).
__global__ __launch_bounds__(256) void main_kernel(const float* __restrict__ demand,
                                                   const float* __restrict__ s1,
                                                   const float* __restrict__ s2,
                                                   float* __restrict__ out) {
    const int wid = threadIdx.x >> 6;
    const int lane = threadIdx.x & 63;
    const long g = (long)blockIdx.x * 4 + wid;   // global row
    const long slice = g >> 9;
    const float s1i = s1[g];
    const float* s2s = s2 + slice * NN;

    const int c0 = lane * 4;
    const int c1 = 256 + lane * 4;
    const float4 sa = *reinterpret_cast<const float4*>(s2s + c0);
    const float4 sb = *reinterpret_cast<const float4*>(s2s + c1);

    const float* drow = demand + g * NN;
    const vf4 d0 = nt_load4(drow + c0);
    const vf4 d1 = nt_load4(drow + c1);

    float pv[8];
    pv[0] = __expf(lrelu(s1i + sa.x));
    pv[1] = __expf(lrelu(s1i + sa.y));
    pv[2] = __expf(lrelu(s1i + sa.z));
    pv[3] = __expf(lrelu(s1i + sa.w));
    pv[4] = __expf(lrelu(s1i + sb.x));
    pv[5] = __expf(lrelu(s1i + sb.y));
    pv[6] = __expf(lrelu(s1i + sb.z));
    pv[7] = __expf(lrelu(s1i + sb.w));

    float sum = 0.f;
    #pragma unroll
    for (int k = 0; k < 8; ++k) sum += pv[k];
    #pragma unroll
    for (int off = 32; off > 0; off >>= 1) sum += __shfl_xor(sum, off);
    const float inv = 1.f / sum;

    vf4 o0, o1;
    o0.x = lrelu(d0.x * pv[0] * inv); o0.y = lrelu(d0.y * pv[1] * inv);
    o0.z = lrelu(d0.z * pv[2] * inv); o0.w = lrelu(d0.w * pv[3] * inv);
    o1.x = lrelu(d1.x * pv[4] * inv); o1.y = lrelu(d1.y * pv[5] * inv);
    o1.z = lrelu(d1.z * pv[6] * inv); o1.w = lrelu(d1.w * pv[7] * inv);

    float* orow = out + g * NN;
    nt_store4(orow + c0, o0);
    nt_store4(orow + c1, o1);
}

extern "C" void kernel_launch(void* const* d_in, const int* in_sizes, int n_in,
                              void* d_out, int out_size, void* d_ws, size_t ws_size,
                              hipStream_t stream) {
    const float* demand  = (const float*)d_in[0];
    const float* st_feat = (const float*)d_in[1];
    const float* W       = (const float*)d_in[2];
    const float* a       = (const float*)d_in[3];
    float* out = (float*)d_out;

    float* wa = (float*)d_ws;                  // 256 floats
    float* s1 = wa + 2 * NWD;                  // NROWS floats
    float* s2 = s1 + NROWS;                    // NROWS floats

    wa_kernel<<<16, 256, 0, stream>>>(W, a, wa);
    s_kernel<<<NROWS / 32, 256, 0, stream>>>(st_feat, wa, s1, s2);
    main_kernel<<<NROWS / 4, 256, 0, stream>>>(demand, s1, s2, out);
}

// Round 12
// 46.726 us; speedup vs baseline: 1.0225x; 1.0225x over previous
//
#include <hip/hip_runtime.h>

#define NN 512
#define NWD 128
#define NSLICES 96                      // B*P*Q
#define NROWS (NSLICES * NN)            // 49152
#define ALPHA 0.2f

__device__ __forceinline__ float lrelu(float x) {
    return x > 0.f ? x : ALPHA * x;
}

// k0: wa1 = W@a1, wa2 = W@a2 -> global ws (256 floats).
// 16 blocks x 256 threads; each wave does ONE coalesced row-pair butterfly.
__global__ __launch_bounds__(256) void wa_kernel(const float* __restrict__ W,
                                                 const float* __restrict__ a,
                                                 float* __restrict__ wa) {
    const int t = threadIdx.x;
    const int wid = t >> 6;
    const int lane = t & 63;
    const int l5 = lane & 31;
    const int half = lane >> 5;

    const int k = (blockIdx.x * 4 + wid) * 2;      // W row pair (k, k+1)
    const float4 a1v = *reinterpret_cast<const float4*>(a + l5 * 4);
    const float4 a2v = *reinterpret_cast<const float4*>(a + NWD + l5 * 4);
    const float4 wv  = *reinterpret_cast<const float4*>(W + (long)k * NWD + lane * 4);

    float p1 = wv.x * a1v.x + wv.y * a1v.y + wv.z * a1v.z + wv.w * a1v.w;
    float p2 = wv.x * a2v.x + wv.y * a2v.y + wv.z * a2v.z + wv.w * a2v.w;
    #pragma unroll
    for (int off = 16; off > 0; off >>= 1) {
        p1 += __shfl_xor(p1, off);
        p2 += __shfl_xor(p2, off);
    }
    if (l5 == 0) {
        wa[k + half] = p1;              // wa1
        wa[NWD + k + half] = p2;        // wa2
    }
}

// k1: s1[g], s2[g] for all rows. 1536 blocks x 32 rows; 4 prefetched
// float4 loads per wave (cached -- nt refuted in R11: L3 retention matters).
__global__ __launch_bounds__(256) void s_kernel(const float* __restrict__ st,
                                                const float* __restrict__ wa,
                                                float* __restrict__ s1,
                                                float* __restrict__ s2) {
    const int t = threadIdx.x;
    const int wid = t >> 6;
    const int lane = t & 63;
    const int l5 = lane & 31;
    const int half = lane >> 5;

    const float4 w1v = *reinterpret_cast<const float4*>(wa + l5 * 4);
    const float4 w2v = *reinterpret_cast<const float4*>(wa + NWD + l5 * 4);
    const long blockbase = (long)blockIdx.x * 32;    // 32 rows per block
    const long wavebase = blockbase + (long)wid * 8; // 8 rows = 4 rowpairs

    float4 f[4];
    #pragma unroll
    for (int i = 0; i < 4; ++i)
        f[i] = *reinterpret_cast<const float4*>(st + (wavebase + i * 2) * NWD + lane * 4);

    #pragma unroll
    for (int i = 0; i < 4; ++i) {
        float p1 = f[i].x * w1v.x + f[i].y * w1v.y + f[i].z * w1v.z + f[i].w * w1v.w;
        float p2 = f[i].x * w2v.x + f[i].y * w2v.y + f[i].z * w2v.z + f[i].w * w2v.w;
        #pragma unroll
        for (int off = 16; off > 0; off >>= 1) {
            p1 += __shfl_xor(p1, off);
            p2 += __shfl_xor(p2, off);
        }
        if (l5 == 0) {
            const long g = wavebase + i * 2 + half;
            s1[g] = p1;
            s2[g] = p2;
        }
    }
}

// k2: streaming kernel, TWO rows per wave (6144 blocks x 4 waves).
//   - one float2 load covers both rows' s1
//   - sa/sb s2 registers serve both rows (halves L1 request rate on the
//     100 MB-aggregate s2 re-read stream)
//   - 4 independent demand float4 loads in flight (64 B/lane)
// No row-max: |e| <= ~15, exp <= 1.2e6 -- f32-safe (validated R6/R7).
__global__ __launch_bounds__(256) void main_kernel(const float* __restrict__ demand,
                                                   const float* __restrict__ s1,
                                                   const float* __restrict__ s2,
                                                   float* __restrict__ out) {
    const int wid = threadIdx.x >> 6;
    const int lane = threadIdx.x & 63;
    const long g0 = ((long)blockIdx.x * 4 + wid) * 2;   // rows g0, g0+1
    const long slice = g0 >> 9;
    const float2 s1p = *reinterpret_cast<const float2*>(s1 + g0);
    const float* s2s = s2 + slice * NN;

    const int c0 = lane * 4;
    const int c1 = 256 + lane * 4;
    const float4 sa = *reinterpret_cast<const float4*>(s2s + c0);
    const float4 sb = *reinterpret_cast<const float4*>(s2s + c1);

    // issue all 4 demand loads up front
    const float* drow0 = demand + g0 * NN;
    const float* drow1 = drow0 + NN;
    const float4 dA0 = *reinterpret_cast<const float4*>(drow0 + c0);
    const float4 dA1 = *reinterpret_cast<const float4*>(drow0 + c1);
    const float4 dB0 = *reinterpret_cast<const float4*>(drow1 + c0);
    const float4 dB1 = *reinterpret_cast<const float4*>(drow1 + c1);

    const float sA = s1p.x, sB = s1p.y;
    float pA[8], pB[8];
    pA[0] = __expf(lrelu(sA + sa.x)); pB[0] = __expf(lrelu(sB + sa.x));
    pA[1] = __expf(lrelu(sA + sa.y)); pB[1] = __expf(lrelu(sB + sa.y));
    pA[2] = __expf(lrelu(sA + sa.z)); pB[2] = __expf(lrelu(sB + sa.z));
    pA[3] = __expf(lrelu(sA + sa.w)); pB[3] = __expf(lrelu(sB + sa.w));
    pA[4] = __expf(lrelu(sA + sb.x)); pB[4] = __expf(lrelu(sB + sb.x));
    pA[5] = __expf(lrelu(sA + sb.y)); pB[5] = __expf(lrelu(sB + sb.y));
    pA[6] = __expf(lrelu(sA + sb.z)); pB[6] = __expf(lrelu(sB + sb.z));
    pA[7] = __expf(lrelu(sA + sb.w)); pB[7] = __expf(lrelu(sB + sb.w));

    float sumA = 0.f, sumB = 0.f;
    #pragma unroll
    for (int k = 0; k < 8; ++k) { sumA += pA[k]; sumB += pB[k]; }
    #pragma unroll
    for (int off = 32; off > 0; off >>= 1) {
        sumA += __shfl_xor(sumA, off);
        sumB += __shfl_xor(sumB, off);
    }
    const float invA = 1.f / sumA;
    const float invB = 1.f / sumB;

    float4 oA0, oA1, oB0, oB1;
    oA0.x = lrelu(dA0.x * pA[0] * invA); oA0.y = lrelu(dA0.y * pA[1] * invA);
    oA0.z = lrelu(dA0.z * pA[2] * invA); oA0.w = lrelu(dA0.w * pA[3] * invA);
    oA1.x = lrelu(dA1.x * pA[4] * invA); oA1.y = lrelu(dA1.y * pA[5] * invA);
    oA1.z = lrelu(dA1.z * pA[6] * invA); oA1.w = lrelu(dA1.w * pA[7] * invA);
    oB0.x = lrelu(dB0.x * pB[0] * invB); oB0.y = lrelu(dB0.y * pB[1] * invB);
    oB0.z = lrelu(dB0.z * pB[2] * invB); oB0.w = lrelu(dB0.w * pB[3] * invB);
    oB1.x = lrelu(dB1.x * pB[4] * invB); oB1.y = lrelu(dB1.y * pB[5] * invB);
    oB1.z = lrelu(dB1.z * pB[6] * invB); oB1.w = lrelu(dB1.w * pB[7] * invB);

    float* orow0 = out + g0 * NN;
    float* orow1 = orow0 + NN;
    *reinterpret_cast<float4*>(orow0 + c0) = oA0;
    *reinterpret_cast<float4*>(orow0 + c1) = oA1;
    *reinterpret_cast<float4*>(orow1 + c0) = oB0;
    *reinterpret_cast<float4*>(orow1 + c1) = oB1;
}

extern "C" void kernel_launch(void* const* d_in, const int* in_sizes, int n_in,
                              void* d_out, int out_size, void* d_ws, size_t ws_size,
                              hipStream_t stream) {
    const float* demand  = (const float*)d_in[0];
    const float* st_feat = (const float*)d_in[1];
    const float* W       = (const float*)d_in[2];
    const float* a       = (const float*)d_in[3];
    float* out = (float*)d_out;

    float* wa = (float*)d_ws;                  // 256 floats
    float* s1 = wa + 2 * NWD;                  // NROWS floats
    float* s2 = s1 + NROWS;                    // NROWS floats

    wa_kernel<<<16, 256, 0, stream>>>(W, a, wa);
    s_kernel<<<NROWS / 32, 256, 0, stream>>>(st_feat, wa, s1, s2);
    main_kernel<<<NROWS / 8, 256, 0, stream>>>(demand, s1, s2, out);
}